// Round 2
// baseline (661.976 us; speedup 1.0000x reference)
//
#include <hip/hip_runtime.h>

typedef unsigned short u16;
typedef unsigned int u32;
using f32x4 = __attribute__((ext_vector_type(4))) float;
using bf16x8 = __attribute__((ext_vector_type(8))) __bf16;

constexpr int Bc = 4, Tc = 2048, Dc = 2048, Hc = 16, Gc = 4, Kc = 128;
constexpr float EPSc = 1e-6f;

__device__ __forceinline__ u16 f2bf(float f) {
    u32 u = __float_as_uint(f);
    u = (u + 0x7fffu + ((u >> 16) & 1u)) >> 16;
    return (u16)u;
}
__device__ __forceinline__ float bf2f(u16 h) {
    return __uint_as_float(((u32)h) << 16);
}

// async global->LDS, 16B per lane; LDS dest must be wave-uniform base + lane*16
__device__ __forceinline__ void async_ld16(void* lds, const void* g) {
    __builtin_amdgcn_global_load_lds(
        (const __attribute__((address_space(1))) unsigned int*)g,
        (__attribute__((address_space(3))) unsigned int*)lds, 16, 0, 0);
}

// ---------------- fp32 -> bf16 convert ----------------
__global__ __launch_bounds__(256) void cvt_f2bf(const float* __restrict__ in,
                                                u16* __restrict__ out, int n) {
    int i = (blockIdx.x * 256 + threadIdx.x) * 4;
    if (i >= n) return;
    float4 f = *(const float4*)(in + i);
    u16 r[4] = { f2bf(f.x), f2bf(f.y), f2bf(f.z), f2bf(f.w) };
    *(uint2*)(out + i) = *(uint2*)r;
}

// ------- transpose+convert: in (rows x cols) f32 -> out (cols x rows) bf16 -------
__global__ __launch_bounds__(256) void transpose_f2bf(const float* __restrict__ in,
                                                      u16* __restrict__ out,
                                                      int rows, int cols) {
    __shared__ float tile[32][33];
    int tx = threadIdx.x & 31, ty = threadIdx.x >> 5;
    int c0 = blockIdx.x * 32, r0 = blockIdx.y * 32;
#pragma unroll
    for (int j = 0; j < 4; j++)
        tile[ty + j * 8][tx] = in[(size_t)(r0 + ty + j * 8) * cols + c0 + tx];
    __syncthreads();
#pragma unroll
    for (int j = 0; j < 4; j++)
        out[(size_t)(c0 + ty + j * 8) * rows + r0 + tx] = f2bf(tile[tx][ty + j * 8]);
}

// ---------------- positions from (sorted) segment ids ----------------
__global__ void pos_kernel(const int* __restrict__ seg, int* __restrict__ pos) {
    int idx = blockIdx.x * 256 + threadIdx.x;
    if (idx >= Bc * Tc) return;
    int b = idx / Tc, t = idx - b * Tc;
    const int* s = seg + b * Tc;
    int v = s[t];
    int lo = 0, hi = t;
    while (lo < hi) { int mid = (lo + hi) >> 1; if (s[mid] < v) lo = mid + 1; else hi = mid; }
    pos[idx] = t - lo;   // t - seg_start
}

// ---------------- bf16 GEMM (m97 structure): C(MxN) = A(MxKd) * Bt(NxKd)^T ----------------
#define GBM 128
#define GBN 128
#define GBK 32

__global__ __launch_bounds__(256) void gemm_bt(const u16* __restrict__ A,
                                               const u16* __restrict__ Bt,
                                               float* __restrict__ Cf, u16* __restrict__ Cb,
                                               int M, int N, int Kd) {
    __shared__ __align__(16) u16 lA[GBM * GBK];   // unpadded: required by global_load_lds lane order
    __shared__ __align__(16) u16 lB[GBN * GBK];
    const int tid = threadIdx.x;
    const int m0 = blockIdx.y * GBM, n0 = blockIdx.x * GBN;
    const int wave = tid >> 6, lane = tid & 63;
    const int l16 = lane & 15, quad = lane >> 4;
    const int wm = (wave & 1) * 64, wn = (wave >> 1) * 64;

    // 16B chunk c: row = c>>2, kchunk = c&3; LDS byte offset = c*16 (contiguous lane order)
    const int c0 = tid, c1 = tid + 256;
    const u16* gA0 = A + (size_t)(m0 + (c0 >> 2)) * Kd + (c0 & 3) * 8;
    const u16* gA1 = A + (size_t)(m0 + (c1 >> 2)) * Kd + (c1 & 3) * 8;
    const u16* gB0 = Bt + (size_t)(n0 + (c0 >> 2)) * Kd + (c0 & 3) * 8;
    const u16* gB1 = Bt + (size_t)(n0 + (c1 >> 2)) * Kd + (c1 & 3) * 8;
    u16* sA0 = &lA[c0 * 8];
    u16* sA1 = &lA[c1 * 8];
    u16* sB0 = &lB[c0 * 8];
    u16* sB1 = &lB[c1 * 8];

    const f32x4 fz = {0.f, 0.f, 0.f, 0.f};
    f32x4 acc[4][4];
#pragma unroll
    for (int i = 0; i < 4; i++)
#pragma unroll
        for (int j = 0; j < 4; j++) acc[i][j] = fz;

    for (int k0 = 0; k0 < Kd; k0 += GBK) {
        __syncthreads();                 // prev iter's LDS reads complete
        async_ld16(sA0, gA0 + k0);
        async_ld16(sA1, gA1 + k0);
        async_ld16(sB0, gB0 + k0);
        async_ld16(sB1, gB1 + k0);
        __syncthreads();                 // drains vmcnt -> staging visible
        bf16x8 af[4], bg[4];
#pragma unroll
        for (int i = 0; i < 4; i++) {
            af[i] = *(const bf16x8*)&lA[(wm + i * 16 + l16) * GBK + quad * 8];
            bg[i] = *(const bf16x8*)&lB[(wn + i * 16 + l16) * GBK + quad * 8];
        }
#pragma unroll
        for (int mi = 0; mi < 4; mi++)
#pragma unroll
            for (int ni = 0; ni < 4; ni++)
                acc[mi][ni] = __builtin_amdgcn_mfma_f32_16x16x32_bf16(af[mi], bg[ni], acc[mi][ni], 0, 0, 0);
    }

#pragma unroll
    for (int mi = 0; mi < 4; mi++)
#pragma unroll
        for (int ni = 0; ni < 4; ni++)
#pragma unroll
            for (int r = 0; r < 4; r++) {
                int row = m0 + wm + mi * 16 + quad * 4 + r;   // C/D: row=quad*4+reg
                int col = n0 + wn + ni * 16 + l16;            //      col=lane&15
                float v = acc[mi][ni][r];
                if (Cf) Cf[(size_t)row * N + col] = v;
                else    Cb[(size_t)row * N + col] = f2bf(v);
            }
}

// ---------------- fused RMSNorm + RoPE, in place on bf16 rows of 128 ----------------
__global__ __launch_bounds__(256) void rms_rope(u16* __restrict__ X,
                                                const float* __restrict__ sc,
                                                const int* __restrict__ pos, int NH) {
    int row = blockIdx.x * 4 + (threadIdx.x >> 6);   // one wave per (b,t,head) row
    int lane = threadIdx.x & 63;
    int bt = row / NH;
    u16* xp = X + (size_t)row * Kc;
    float x1 = bf2f(xp[lane]), x2 = bf2f(xp[lane + 64]);   // rope pairs (j, j+64)
    float ss = x1 * x1 + x2 * x2;
#pragma unroll
    for (int m = 1; m < 64; m <<= 1) ss += __shfl_xor(ss, m, 64);
    float rn = rsqrtf(ss * (1.f / 128.f) + EPSc);
    float y1 = x1 * rn * sc[lane];
    float y2 = x2 * rn * sc[lane + 64];
    float inv_freq = expf(-logf(10000.f) * ((float)(2 * lane) * (1.f / 128.f)));
    float ang = (float)pos[bt] * inv_freq;
    float sv, cv;
    sincosf(ang, &sv, &cv);
    xp[lane]      = f2bf(y1 * cv - y2 * sv);
    xp[lane + 64] = f2bf(y2 * cv + y1 * sv);
}

// ---------------- flash attention: 64 q-rows per block, 64-wide s-tiles ----------------
// LDS strides in u16; stride/2 mod 32 == 4 -> 16 lanes over 8 banks = 2-way (free)
#define KSTR 136   // 128+8
#define VSTR 72    // 64+8
#define PSTR 72

__global__ __launch_bounds__(256, 3) void flash_attn(const u16* __restrict__ Qb,
                                                     const u16* __restrict__ Kb,
                                                     const u16* __restrict__ Vb,
                                                     const int* __restrict__ seg,
                                                     const int* __restrict__ pos,
                                                     u16* __restrict__ Ob) {
    __shared__ __align__(16) u16 lK[64 * KSTR];
    __shared__ __align__(16) u16 lVt[128 * VSTR];   // V transposed: [d][s]
    __shared__ __align__(16) u16 lP[64 * PSTR];     // [t][s]
    __shared__ float lAl[64];                        // alpha per t-row (this iter)
    __shared__ float lLi[64];                        // final l_i per t-row

    const int b = blockIdx.z, h = blockIdx.y, g = h >> 2;     // g = h / R, R=4
    const int q0 = ((int)gridDim.x - 1 - (int)blockIdx.x) * 64;  // heavy tiles first
    const int tid = threadIdx.x;
    const int wave = tid >> 6, lane = tid & 63;
    const int l16 = lane & 15, quad = lane >> 4;
    const float scale = 0.08838834764831845f;   // K^-0.5

    // Q A-fragments in registers: rows q0 + wave*16 + l16, k = kk*32 + quad*8
    bf16x8 qf[4];
#pragma unroll
    for (int kk = 0; kk < 4; kk++)
        qf[kk] = *(const bf16x8*)&Qb[((size_t)(b * Tc + q0 + wave * 16 + l16) * Hc + h) * Kc + kk * 32 + quad * 8];

    int tg[4], sgt[4];
#pragma unroll
    for (int r = 0; r < 4; r++) {
        tg[r] = q0 + wave * 16 + quad * 4 + r;
        sgt[r] = seg[b * Tc + tg[r]];
    }

    float m_i[4], l_i[4];
#pragma unroll
    for (int r = 0; r < 4; r++) { m_i[r] = -1e30f; l_i[r] = 0.f; }
    const f32x4 fz = {0.f, 0.f, 0.f, 0.f};
    f32x4 oc[8];   // O^T C-tiles: row d = ni*16+quad*4+r, col t = wave*16+l16
#pragma unroll
    for (int i = 0; i < 8; i++) oc[i] = fz;

    // segments sorted => valid s range is [seg_start(q0), q-tile end]
    const int s_begin = ((q0 - pos[b * Tc + q0]) >> 6) << 6;

    // prefetch first K/V tile into registers
    uint4 kpre[4], vpre[4];
#pragma unroll
    for (int it = 0; it < 4; it++) {
        int c = tid + it * 256;
        kpre[it] = *(const uint4*)&Kb[((size_t)(b * Tc + s_begin + (c >> 4)) * Gc + g) * Kc + (c & 15) * 8];
        vpre[it] = *(const uint4*)&Vb[((size_t)(b * Tc + s_begin + (c & 63)) * Gc + g) * Kc + (c >> 6) * 8];
    }

    for (int s0 = s_begin; s0 <= q0; s0 += 64) {
        __syncthreads();   // prior iter's lK/lVt/lP reads complete
        // stage K tile (64 x 128) from prefetch regs
#pragma unroll
        for (int it = 0; it < 4; it++) {
            int c = tid + it * 256;
            *(uint4*)&lK[(c >> 4) * KSTR + (c & 15) * 8] = kpre[it];
        }
        // stage V transposed [d][s]
#pragma unroll
        for (int it = 0; it < 4; it++) {
            int c = tid + it * 256;
            int s = c & 63, dc = (c >> 6) * 8;
            u16 tmp[8];
            *(uint4*)tmp = vpre[it];
#pragma unroll
            for (int j = 0; j < 8; j++) lVt[(dc + j) * VSTR + s] = tmp[j];
        }
        // prefetch next tile (overlaps this iter's compute)
        if (s0 + 64 <= q0) {
#pragma unroll
            for (int it = 0; it < 4; it++) {
                int c = tid + it * 256;
                kpre[it] = *(const uint4*)&Kb[((size_t)(b * Tc + s0 + 64 + (c >> 4)) * Gc + g) * Kc + (c & 15) * 8];
                vpre[it] = *(const uint4*)&Vb[((size_t)(b * Tc + s0 + 64 + (c & 63)) * Gc + g) * Kc + (c >> 6) * 8];
            }
        }
        __syncthreads();   // staging visible

        // S = Q K^T : per-wave 16 t-rows x 64 s-cols (C layout: row t=quad*4+r, col s=l16)
        f32x4 sacc[4];
#pragma unroll
        for (int nj = 0; nj < 4; nj++) sacc[nj] = fz;
#pragma unroll
        for (int kk = 0; kk < 4; kk++) {
#pragma unroll
            for (int nj = 0; nj < 4; nj++) {
                bf16x8 bk = *(const bf16x8*)&lK[(nj * 16 + l16) * KSTR + kk * 32 + quad * 8];
                sacc[nj] = __builtin_amdgcn_mfma_f32_16x16x32_bf16(qf[kk], bk, sacc[nj], 0, 0, 0);
            }
        }

        int sgs[4];
#pragma unroll
        for (int nj = 0; nj < 4; nj++) sgs[nj] = seg[b * Tc + s0 + nj * 16 + l16];

        // mask + online softmax
        float xv[4][4], rmax[4];
#pragma unroll
        for (int r = 0; r < 4; r++) rmax[r] = -1e30f;
#pragma unroll
        for (int nj = 0; nj < 4; nj++) {
            int sIdx = s0 + nj * 16 + l16;
#pragma unroll
            for (int r = 0; r < 4; r++) {
                bool ok = (sIdx <= tg[r]) && (sgs[nj] == sgt[r]);
                float x = ok ? sacc[nj][r] * scale : -1e30f;
                xv[nj][r] = x;
                rmax[r] = fmaxf(rmax[r], x);
            }
        }
#pragma unroll
        for (int r = 0; r < 4; r++) {
            float v = rmax[r];
            v = fmaxf(v, __shfl_xor(v, 1, 64));
            v = fmaxf(v, __shfl_xor(v, 2, 64));
            v = fmaxf(v, __shfl_xor(v, 4, 64));
            v = fmaxf(v, __shfl_xor(v, 8, 64));
            rmax[r] = v;
        }
        float alpha[4];
#pragma unroll
        for (int r = 0; r < 4; r++) {
            float mnew = fmaxf(m_i[r], rmax[r]);
            alpha[r] = __expf(m_i[r] - mnew);
            m_i[r] = mnew;
        }
        // broadcast alpha (C-layout rows) -> per-t LDS strip for PV layout
#pragma unroll
        for (int r = 0; r < 4; r++)
            if (l16 == r) lAl[wave * 16 + quad * 4 + r] = alpha[r];

        float psum[4] = {0.f, 0.f, 0.f, 0.f};
#pragma unroll
        for (int nj = 0; nj < 4; nj++) {
#pragma unroll
            for (int r = 0; r < 4; r++) {
                float x = xv[nj][r];
                float p = (x > -1e29f) ? __expf(x - m_i[r]) : 0.f;   // masked -> exactly 0
                psum[r] += p;
                lP[(wave * 16 + quad * 4 + r) * PSTR + nj * 16 + l16] = f2bf(p);
            }
        }
#pragma unroll
        for (int r = 0; r < 4; r++) {
            float v = psum[r];
            v += __shfl_xor(v, 1, 64);
            v += __shfl_xor(v, 2, 64);
            v += __shfl_xor(v, 4, 64);
            v += __shfl_xor(v, 8, 64);
            l_i[r] = l_i[r] * alpha[r] + v;
        }

        // O^T += V^T P^T  (A = Vt[d][s], B = P[t][s]; wave reads ONLY ITS OWN lP rows
        // and its own lAl entries -> no barrier needed, intra-wave ds ordering suffices)
        float alphaL = lAl[wave * 16 + l16];
#pragma unroll
        for (int ni = 0; ni < 8; ni++)
#pragma unroll
            for (int r = 0; r < 4; r++) oc[ni][r] *= alphaL;
#pragma unroll
        for (int kk = 0; kk < 2; kk++) {
            bf16x8 bp = *(const bf16x8*)&lP[(wave * 16 + l16) * PSTR + kk * 32 + quad * 8];
#pragma unroll
            for (int ni = 0; ni < 8; ni++) {
                bf16x8 av = *(const bf16x8*)&lVt[(ni * 16 + l16) * VSTR + kk * 32 + quad * 8];
                oc[ni] = __builtin_amdgcn_mfma_f32_16x16x32_bf16(av, bp, oc[ni], 0, 0, 0);
            }
        }
    }

    // epilogue: O[t][d] = oc / l_i[t];  t = wave*16+l16, d = ni*16+quad*4+r (r consecutive)
#pragma unroll
    for (int r = 0; r < 4; r++)
        if (l16 == r) lLi[wave * 16 + quad * 4 + r] = l_i[r];
    float invl = 1.f / lLi[wave * 16 + l16];
    size_t obase = ((size_t)(b * Tc + q0 + wave * 16 + l16) * Hc + h) * Kc;
#pragma unroll
    for (int ni = 0; ni < 8; ni++) {
        u16 r4[4];
#pragma unroll
        for (int r = 0; r < 4; r++) r4[r] = f2bf(oc[ni][r] * invl);
        *(uint2*)&Ob[obase + ni * 16 + quad * 4] = *(uint2*)r4;
    }
}

extern "C" void kernel_launch(void* const* d_in, const int* in_sizes, int n_in,
                              void* d_out, int out_size, void* d_ws, size_t ws_size,
                              hipStream_t stream) {
    const float* hidden  = (const float*)d_in[0];
    const float* wq      = (const float*)d_in[1];
    const float* wk      = (const float*)d_in[2];
    const float* wv      = (const float*)d_in[3];
    const float* wo      = (const float*)d_in[4];
    const float* q_scale = (const float*)d_in[5];
    const float* k_scale = (const float*)d_in[6];
    const int*   segids  = (const int*)d_in[7];
    float* out = (float*)d_out;

    char* ws = (char*)d_ws;
    size_t off = 0;
    auto alloc = [&](size_t bytes) -> void* {
        void* p = ws + off;
        off += (bytes + 255) & ~(size_t)255;
        return p;
    };
    u16* hbf  = (u16*)alloc((size_t)Bc * Tc * Dc * 2);        // hidden bf16
    u16* wqT  = (u16*)alloc((size_t)Hc * Kc * Dc * 2);        // (2048 x 2048)
    u16* wkT  = (u16*)alloc((size_t)Gc * Kc * Dc * 2);        // (512 x 2048)
    u16* wvT  = (u16*)alloc((size_t)Gc * Kc * Dc * 2);
    u16* woT  = (u16*)alloc((size_t)Dc * Hc * Kc * 2);        // (2048 x 2048)
    u16* qb   = (u16*)alloc((size_t)Bc * Tc * Hc * Kc * 2);
    u16* kb   = (u16*)alloc((size_t)Bc * Tc * Gc * Kc * 2);
    u16* vb   = (u16*)alloc((size_t)Bc * Tc * Gc * Kc * 2);
    u16* attn = (u16*)alloc((size_t)Bc * Tc * Hc * Kc * 2);
    int* posb = (int*)alloc((size_t)Bc * Tc * 4);
    (void)ws_size; (void)in_sizes; (void)n_in; (void)out_size;

    const int M = Bc * Tc;   // 8192

    cvt_f2bf<<<(Bc * Tc * Dc) / 1024, 256, 0, stream>>>(hidden, hbf, Bc * Tc * Dc);
    transpose_f2bf<<<dim3(64, 64), 256, 0, stream>>>(wq, wqT, Dc, Hc * Kc);
    transpose_f2bf<<<dim3(16, 64), 256, 0, stream>>>(wk, wkT, Dc, Gc * Kc);
    transpose_f2bf<<<dim3(16, 64), 256, 0, stream>>>(wv, wvT, Dc, Gc * Kc);
    transpose_f2bf<<<dim3(64, 64), 256, 0, stream>>>(wo, woT, Hc * Kc, Dc);
    pos_kernel<<<(Bc * Tc) / 256, 256, 0, stream>>>(segids, posb);

    gemm_bt<<<dim3((Hc * Kc) / GBN, M / GBM), 256, 0, stream>>>(hbf, wqT, nullptr, qb, M, Hc * Kc, Dc);
    gemm_bt<<<dim3((Gc * Kc) / GBN, M / GBM), 256, 0, stream>>>(hbf, wkT, nullptr, kb, M, Gc * Kc, Dc);
    gemm_bt<<<dim3((Gc * Kc) / GBN, M / GBM), 256, 0, stream>>>(hbf, wvT, nullptr, vb, M, Gc * Kc, Dc);

    rms_rope<<<(M * Hc) / 4, 256, 0, stream>>>(qb, q_scale, posb, Hc);
    rms_rope<<<(M * Gc) / 4, 256, 0, stream>>>(kb, k_scale, posb, Gc);

    flash_attn<<<dim3(Tc / 64, Hc, Bc), 256, 0, stream>>>(qb, kb, vb, segids, posb, attn);

    gemm_bt<<<dim3(Dc / GBN, M / GBM), 256, 0, stream>>>(attn, woT, out, nullptr, M, Dc, Hc * Kc);
}

// Round 4
// 647.252 us; speedup vs baseline: 1.0227x; 1.0227x over previous
//
#include <hip/hip_runtime.h>

typedef unsigned short u16;
typedef unsigned int u32;
using f32x4 = __attribute__((ext_vector_type(4))) float;
using bf16x8 = __attribute__((ext_vector_type(8))) __bf16;

constexpr int Bc = 4, Tc = 2048, Dc = 2048, Hc = 16, Gc = 4, Kc = 128;
constexpr float EPSc = 1e-6f;

__device__ __forceinline__ u16 f2bf(float f) {
    u32 u = __float_as_uint(f);
    u = (u + 0x7fffu + ((u >> 16) & 1u)) >> 16;
    return (u16)u;
}
__device__ __forceinline__ float bf2f(u16 h) {
    return __uint_as_float(((u32)h) << 16);
}

// async global->LDS, 16B per lane; LDS dest must be wave-uniform base + lane*16
__device__ __forceinline__ void async_ld16(void* lds, const void* g) {
    __builtin_amdgcn_global_load_lds(
        (const __attribute__((address_space(1))) unsigned int*)g,
        (__attribute__((address_space(3))) unsigned int*)lds, 16, 0, 0);
}

// ---------------- fp32 -> bf16 convert ----------------
__global__ __launch_bounds__(256) void cvt_f2bf(const float* __restrict__ in,
                                                u16* __restrict__ out, int n) {
    int i = (blockIdx.x * 256 + threadIdx.x) * 4;
    if (i >= n) return;
    float4 f = *(const float4*)(in + i);
    u16 r[4] = { f2bf(f.x), f2bf(f.y), f2bf(f.z), f2bf(f.w) };
    *(uint2*)(out + i) = *(uint2*)r;
}

// ------- transpose+convert: in (rows x cols) f32 -> out (cols x rows) bf16 -------
__global__ __launch_bounds__(256) void transpose_f2bf(const float* __restrict__ in,
                                                      u16* __restrict__ out,
                                                      int rows, int cols) {
    __shared__ float tile[32][33];
    int tx = threadIdx.x & 31, ty = threadIdx.x >> 5;
    int c0 = blockIdx.x * 32, r0 = blockIdx.y * 32;
#pragma unroll
    for (int j = 0; j < 4; j++)
        tile[ty + j * 8][tx] = in[(size_t)(r0 + ty + j * 8) * cols + c0 + tx];
    __syncthreads();
#pragma unroll
    for (int j = 0; j < 4; j++)
        out[(size_t)(c0 + ty + j * 8) * rows + r0 + tx] = f2bf(tile[tx][ty + j * 8]);
}

// ---------------- positions from (sorted) segment ids ----------------
__global__ void pos_kernel(const int* __restrict__ seg, int* __restrict__ pos) {
    int idx = blockIdx.x * 256 + threadIdx.x;
    if (idx >= Bc * Tc) return;
    int b = idx / Tc, t = idx - b * Tc;
    const int* s = seg + b * Tc;
    int v = s[t];
    int lo = 0, hi = t;
    while (lo < hi) { int mid = (lo + hi) >> 1; if (s[mid] < v) lo = mid + 1; else hi = mid; }
    pos[idx] = t - lo;   // t - seg_start
}

// ---------------- bf16 GEMM (m97 structure): C(MxN) = A(MxKd) * Bt(NxKd)^T ----------------
#define GBM 128
#define GBN 128
#define GBK 32

__global__ __launch_bounds__(256) void gemm_bt(const u16* __restrict__ A,
                                               const u16* __restrict__ Bt,
                                               float* __restrict__ Cf, u16* __restrict__ Cb,
                                               int M, int N, int Kd) {
    __shared__ __align__(16) u16 lA[GBM * GBK];   // unpadded: required by global_load_lds lane order
    __shared__ __align__(16) u16 lB[GBN * GBK];
    const int tid = threadIdx.x;
    const int m0 = blockIdx.y * GBM, n0 = blockIdx.x * GBN;
    const int wave = tid >> 6, lane = tid & 63;
    const int l16 = lane & 15, quad = lane >> 4;
    const int wm = (wave & 1) * 64, wn = (wave >> 1) * 64;

    const int c0 = tid, c1 = tid + 256;
    const u16* gA0 = A + (size_t)(m0 + (c0 >> 2)) * Kd + (c0 & 3) * 8;
    const u16* gA1 = A + (size_t)(m0 + (c1 >> 2)) * Kd + (c1 & 3) * 8;
    const u16* gB0 = Bt + (size_t)(n0 + (c0 >> 2)) * Kd + (c0 & 3) * 8;
    const u16* gB1 = Bt + (size_t)(n0 + (c1 >> 2)) * Kd + (c1 & 3) * 8;
    u16* sA0 = &lA[c0 * 8];
    u16* sA1 = &lA[c1 * 8];
    u16* sB0 = &lB[c0 * 8];
    u16* sB1 = &lB[c1 * 8];

    const f32x4 fz = {0.f, 0.f, 0.f, 0.f};
    f32x4 acc[4][4];
#pragma unroll
    for (int i = 0; i < 4; i++)
#pragma unroll
        for (int j = 0; j < 4; j++) acc[i][j] = fz;

    for (int k0 = 0; k0 < Kd; k0 += GBK) {
        __syncthreads();
        async_ld16(sA0, gA0 + k0);
        async_ld16(sA1, gA1 + k0);
        async_ld16(sB0, gB0 + k0);
        async_ld16(sB1, gB1 + k0);
        __syncthreads();
        bf16x8 af[4], bg[4];
#pragma unroll
        for (int i = 0; i < 4; i++) {
            af[i] = *(const bf16x8*)&lA[(wm + i * 16 + l16) * GBK + quad * 8];
            bg[i] = *(const bf16x8*)&lB[(wn + i * 16 + l16) * GBK + quad * 8];
        }
#pragma unroll
        for (int mi = 0; mi < 4; mi++)
#pragma unroll
            for (int ni = 0; ni < 4; ni++)
                acc[mi][ni] = __builtin_amdgcn_mfma_f32_16x16x32_bf16(af[mi], bg[ni], acc[mi][ni], 0, 0, 0);
    }

#pragma unroll
    for (int mi = 0; mi < 4; mi++)
#pragma unroll
        for (int ni = 0; ni < 4; ni++)
#pragma unroll
            for (int r = 0; r < 4; r++) {
                int row = m0 + wm + mi * 16 + quad * 4 + r;   // C/D: row=quad*4+reg
                int col = n0 + wn + ni * 16 + l16;            //      col=lane&15
                float v = acc[mi][ni][r];
                if (Cf) Cf[(size_t)row * N + col] = v;
                else    Cb[(size_t)row * N + col] = f2bf(v);
            }
}

// ------------- fused K+V GEMM: N=1024; K half -> kb natural, V half -> Vt[b][g][d][t] -------------
__global__ __launch_bounds__(256) void gemm_kv(const u16* __restrict__ A,
                                               const u16* __restrict__ Bt,
                                               u16* __restrict__ kb, u16* __restrict__ vtb,
                                               int M, int Kd) {
    __shared__ __align__(16) u16 lA[GBM * GBK];
    __shared__ __align__(16) u16 lB[GBN * GBK];
    const int tid = threadIdx.x;
    const int m0 = blockIdx.y * GBM, n0 = blockIdx.x * GBN;
    const int wave = tid >> 6, lane = tid & 63;
    const int l16 = lane & 15, quad = lane >> 4;
    const int wm = (wave & 1) * 64, wn = (wave >> 1) * 64;

    const int c0 = tid, c1 = tid + 256;
    const u16* gA0 = A + (size_t)(m0 + (c0 >> 2)) * Kd + (c0 & 3) * 8;
    const u16* gA1 = A + (size_t)(m0 + (c1 >> 2)) * Kd + (c1 & 3) * 8;
    const u16* gB0 = Bt + (size_t)(n0 + (c0 >> 2)) * Kd + (c0 & 3) * 8;
    const u16* gB1 = Bt + (size_t)(n0 + (c1 >> 2)) * Kd + (c1 & 3) * 8;
    u16* sA0 = &lA[c0 * 8];
    u16* sA1 = &lA[c1 * 8];
    u16* sB0 = &lB[c0 * 8];
    u16* sB1 = &lB[c1 * 8];

    const f32x4 fz = {0.f, 0.f, 0.f, 0.f};
    f32x4 acc[4][4];
#pragma unroll
    for (int i = 0; i < 4; i++)
#pragma unroll
        for (int j = 0; j < 4; j++) acc[i][j] = fz;

    for (int k0 = 0; k0 < Kd; k0 += GBK) {
        __syncthreads();
        async_ld16(sA0, gA0 + k0);
        async_ld16(sA1, gA1 + k0);
        async_ld16(sB0, gB0 + k0);
        async_ld16(sB1, gB1 + k0);
        __syncthreads();
        bf16x8 af[4], bg[4];
#pragma unroll
        for (int i = 0; i < 4; i++) {
            af[i] = *(const bf16x8*)&lA[(wm + i * 16 + l16) * GBK + quad * 8];
            bg[i] = *(const bf16x8*)&lB[(wn + i * 16 + l16) * GBK + quad * 8];
        }
#pragma unroll
        for (int mi = 0; mi < 4; mi++)
#pragma unroll
            for (int ni = 0; ni < 4; ni++)
                acc[mi][ni] = __builtin_amdgcn_mfma_f32_16x16x32_bf16(af[mi], bg[ni], acc[mi][ni], 0, 0, 0);
    }

    if (n0 < 512) {
        // K half: natural kb[(b,t)][(g,d)] = [M][512]
#pragma unroll
        for (int mi = 0; mi < 4; mi++)
#pragma unroll
            for (int ni = 0; ni < 4; ni++)
#pragma unroll
                for (int r = 0; r < 4; r++) {
                    int row = m0 + wm + mi * 16 + quad * 4 + r;
                    int col = n0 + wn + ni * 16 + l16;
                    kb[(size_t)row * 512 + col] = f2bf(acc[mi][ni][r]);
                }
    } else {
        // V half: transposed Vt[b][g][d][t]; 4 consecutive t per lane -> 8B store
#pragma unroll
        for (int mi = 0; mi < 4; mi++)
#pragma unroll
            for (int ni = 0; ni < 4; ni++) {
                int nv = n0 + wn + ni * 16 + l16 - 512;
                int g = nv >> 7, d = nv & 127;
                int m = m0 + wm + mi * 16 + quad * 4;
                int b = m >> 11, t = m & 2047;
                u16 r4[4];
#pragma unroll
                for (int r = 0; r < 4; r++) r4[r] = f2bf(acc[mi][ni][r]);
                *(uint2*)&vtb[(((size_t)b * Gc + g) * Kc + d) * Tc + t] = *(uint2*)r4;
            }
    }
}

// ---------------- fused RMSNorm + RoPE, in place on bf16 rows of 128 ----------------
__global__ __launch_bounds__(256) void rms_rope(u16* __restrict__ X,
                                                const float* __restrict__ sc,
                                                const int* __restrict__ pos, int NH) {
    int row = blockIdx.x * 4 + (threadIdx.x >> 6);   // one wave per (b,t,head) row
    int lane = threadIdx.x & 63;
    int bt = row / NH;
    u16* xp = X + (size_t)row * Kc;
    float x1 = bf2f(xp[lane]), x2 = bf2f(xp[lane + 64]);   // rope pairs (j, j+64)
    float ss = x1 * x1 + x2 * x2;
#pragma unroll
    for (int m = 1; m < 64; m <<= 1) ss += __shfl_xor(ss, m, 64);
    float rn = rsqrtf(ss * (1.f / 128.f) + EPSc);
    float y1 = x1 * rn * sc[lane];
    float y2 = x2 * rn * sc[lane + 64];
    float inv_freq = expf(-logf(10000.f) * ((float)(2 * lane) * (1.f / 128.f)));
    float ang = (float)pos[bt] * inv_freq;
    float sv, cv;
    sincosf(ang, &sv, &cv);
    xp[lane]      = f2bf(y1 * cv - y2 * sv);
    xp[lane + 64] = f2bf(y2 * cv + y1 * sv);
}

// ---------------- flash attention: 64 q-rows per block, 64-wide s-tiles ----------------
#define KSTR 136   // 128+8: stride 68 dwords == 4 mod 32 -> 2-way on frag reads (free)
#define VSTR 72    // 64+8:  stride 36 dwords == 4 mod 32
#define PSTR 72

__global__ __launch_bounds__(256) void flash_attn(const u16* __restrict__ Qb,
                                                  const u16* __restrict__ Kb,
                                                  const u16* __restrict__ Vt,
                                                  const int* __restrict__ seg,
                                                  const int* __restrict__ pos,
                                                  u16* __restrict__ Ob) {
    __shared__ __align__(16) u16 lK[64 * KSTR];
    __shared__ __align__(16) u16 lVt[128 * VSTR];   // V transposed: [d][s]
    __shared__ __align__(16) u16 lP[64 * PSTR];     // [t][s]
    __shared__ float lAl[64];
    __shared__ float lLi[64];

    const int b = blockIdx.z, h = blockIdx.y, g = h >> 2;        // g = h / R, R=4
    const int q0 = ((int)gridDim.x - 1 - (int)blockIdx.x) * 64;  // heavy tiles first
    const int tid = threadIdx.x;
    const int wave = tid >> 6, lane = tid & 63;
    const int l16 = lane & 15, quad = lane >> 4;
    const float scale = 0.08838834764831845f;   // K^-0.5

    // Q A-fragments in registers
    bf16x8 qf[4];
#pragma unroll
    for (int kk = 0; kk < 4; kk++)
        qf[kk] = *(const bf16x8*)&Qb[((size_t)(b * Tc + q0 + wave * 16 + l16) * Hc + h) * Kc + kk * 32 + quad * 8];

    int tg[4], sgt[4];
#pragma unroll
    for (int r = 0; r < 4; r++) {
        tg[r] = q0 + wave * 16 + quad * 4 + r;
        sgt[r] = seg[b * Tc + tg[r]];
    }
    const bool segQuni = (seg[b * Tc + q0] == seg[b * Tc + q0 + 63]);

    float m_i[4], l_i[4];
#pragma unroll
    for (int r = 0; r < 4; r++) { m_i[r] = -1e30f; l_i[r] = 0.f; }
    const f32x4 fz = {0.f, 0.f, 0.f, 0.f};
    f32x4 oc[8];   // O^T C-tiles: row d = ni*16+quad*4+r, col t = wave*16+l16
#pragma unroll
    for (int i = 0; i < 8; i++) oc[i] = fz;

    const int seg_start_exact = q0 - pos[b * Tc + q0];   // first index of q0's segment
    const int s_begin = (seg_start_exact >> 6) << 6;     // tile-aligned (may include prev segment!)

    for (int s0 = s_begin; s0 <= q0; s0 += 64) {
        __syncthreads();   // prior iter's lK/lVt/lP reads complete
        // stage K tile (64 x 128), natural layout, padded stride
#pragma unroll
        for (int it = 0; it < 4; it++) {
            int c = tid + it * 256;
            *(uint4*)&lK[(c >> 4) * KSTR + (c & 15) * 8] =
                *(const uint4*)&Kb[((size_t)(b * Tc + s0 + (c >> 4)) * Gc + g) * Kc + (c & 15) * 8];
        }
        // stage Vt tile (128 x 64) from pre-transposed global: pure uint4 copies
#pragma unroll
        for (int it = 0; it < 4; it++) {
            int c = tid + it * 256;
            int d = c >> 3, sc = c & 7;
            *(uint4*)&lVt[d * VSTR + sc * 8] =
                *(const uint4*)&Vt[(((size_t)b * Gc + g) * Kc + d) * Tc + s0 + sc * 8];
        }
        __syncthreads();

        // S = Q K^T
        f32x4 sacc[4];
#pragma unroll
        for (int nj = 0; nj < 4; nj++) sacc[nj] = fz;
#pragma unroll
        for (int kk = 0; kk < 4; kk++) {
#pragma unroll
            for (int nj = 0; nj < 4; nj++) {
                bf16x8 bk = *(const bf16x8*)&lK[(nj * 16 + l16) * KSTR + kk * 32 + quad * 8];
                sacc[nj] = __builtin_amdgcn_mfma_f32_16x16x32_bf16(qf[kk], bk, sacc[nj], 0, 0, 0);
            }
        }

        // Fast path is valid only when the whole s-tile provably passes both checks:
        //   causal:  s0+63 < q0 <= all t  <=>  s0+64 <= q0
        //   segment: all s in [seg_start_exact, q0] AND q-tile segment-uniform
        //            (s0 >= seg_start_exact matters: s_begin is rounded DOWN and its
        //             tile can contain tokens from the previous segment)
        const bool fast = segQuni && (s0 >= seg_start_exact) && (s0 + 64 <= q0);
        float rmax[4];
#pragma unroll
        for (int r = 0; r < 4; r++) rmax[r] = -1e30f;
        if (fast) {
#pragma unroll
            for (int nj = 0; nj < 4; nj++)
#pragma unroll
                for (int r = 0; r < 4; r++) {
                    float x = sacc[nj][r] * scale;
                    sacc[nj][r] = x;
                    rmax[r] = fmaxf(rmax[r], x);
                }
        } else {
            int sgs[4];
#pragma unroll
            for (int nj = 0; nj < 4; nj++) sgs[nj] = seg[b * Tc + s0 + nj * 16 + l16];
#pragma unroll
            for (int nj = 0; nj < 4; nj++) {
                int sIdx = s0 + nj * 16 + l16;
#pragma unroll
                for (int r = 0; r < 4; r++) {
                    bool ok = (sIdx <= tg[r]) && (sgs[nj] == sgt[r]);
                    float x = ok ? sacc[nj][r] * scale : -1e30f;
                    sacc[nj][r] = x;
                    rmax[r] = fmaxf(rmax[r], x);
                }
            }
        }
#pragma unroll
        for (int r = 0; r < 4; r++) {
            float v = rmax[r];
            v = fmaxf(v, __shfl_xor(v, 1, 64));
            v = fmaxf(v, __shfl_xor(v, 2, 64));
            v = fmaxf(v, __shfl_xor(v, 4, 64));
            v = fmaxf(v, __shfl_xor(v, 8, 64));
            rmax[r] = v;
        }
        float alpha[4];
#pragma unroll
        for (int r = 0; r < 4; r++) {
            float mnew = fmaxf(m_i[r], rmax[r]);
            alpha[r] = __expf(m_i[r] - mnew);
            m_i[r] = mnew;
        }
#pragma unroll
        for (int r = 0; r < 4; r++)
            if (l16 == r) lAl[wave * 16 + quad * 4 + r] = alpha[r];

        float psum[4] = {0.f, 0.f, 0.f, 0.f};
#pragma unroll
        for (int nj = 0; nj < 4; nj++) {
#pragma unroll
            for (int r = 0; r < 4; r++) {
                float x = sacc[nj][r];
                float p = (x > -1e29f) ? __expf(x - m_i[r]) : 0.f;
                psum[r] += p;
                lP[(wave * 16 + quad * 4 + r) * PSTR + nj * 16 + l16] = f2bf(p);
            }
        }
#pragma unroll
        for (int r = 0; r < 4; r++) {
            float v = psum[r];
            v += __shfl_xor(v, 1, 64);
            v += __shfl_xor(v, 2, 64);
            v += __shfl_xor(v, 4, 64);
            v += __shfl_xor(v, 8, 64);
            l_i[r] = l_i[r] * alpha[r] + v;
        }

        // O^T += V^T P^T (wave reads only its own lP rows / lAl entries: no barrier)
        float alphaL = lAl[wave * 16 + l16];
#pragma unroll
        for (int ni = 0; ni < 8; ni++)
#pragma unroll
            for (int r = 0; r < 4; r++) oc[ni][r] *= alphaL;
#pragma unroll
        for (int kk = 0; kk < 2; kk++) {
            bf16x8 bp = *(const bf16x8*)&lP[(wave * 16 + l16) * PSTR + kk * 32 + quad * 8];
#pragma unroll
            for (int ni = 0; ni < 8; ni++) {
                bf16x8 av = *(const bf16x8*)&lVt[(ni * 16 + l16) * VSTR + kk * 32 + quad * 8];
                oc[ni] = __builtin_amdgcn_mfma_f32_16x16x32_bf16(av, bp, oc[ni], 0, 0, 0);
            }
        }
    }

    // epilogue: O[t][d] = oc / l_i[t]
#pragma unroll
    for (int r = 0; r < 4; r++)
        if (l16 == r) lLi[wave * 16 + quad * 4 + r] = l_i[r];
    float invl = 1.f / lLi[wave * 16 + l16];
    size_t obase = ((size_t)(b * Tc + q0 + wave * 16 + l16) * Hc + h) * Kc;
#pragma unroll
    for (int ni = 0; ni < 8; ni++) {
        u16 r4[4];
#pragma unroll
        for (int r = 0; r < 4; r++) r4[r] = f2bf(oc[ni][r] * invl);
        *(uint2*)&Ob[obase + ni * 16 + quad * 4] = *(uint2*)r4;
    }
}

extern "C" void kernel_launch(void* const* d_in, const int* in_sizes, int n_in,
                              void* d_out, int out_size, void* d_ws, size_t ws_size,
                              hipStream_t stream) {
    const float* hidden  = (const float*)d_in[0];
    const float* wq      = (const float*)d_in[1];
    const float* wk      = (const float*)d_in[2];
    const float* wv      = (const float*)d_in[3];
    const float* wo      = (const float*)d_in[4];
    const float* q_scale = (const float*)d_in[5];
    const float* k_scale = (const float*)d_in[6];
    const int*   segids  = (const int*)d_in[7];
    float* out = (float*)d_out;

    char* ws = (char*)d_ws;
    size_t off = 0;
    auto alloc = [&](size_t bytes) -> void* {
        void* p = ws + off;
        off += (bytes + 255) & ~(size_t)255;
        return p;
    };
    u16* hbf  = (u16*)alloc((size_t)Bc * Tc * Dc * 2);        // hidden bf16
    u16* wqT  = (u16*)alloc((size_t)Hc * Kc * Dc * 2);        // (2048 x 2048)
    u16* wkT  = (u16*)alloc((size_t)Gc * Kc * Dc * 2);        // (512 x 2048) -- adjacent to wvT
    u16* wvT  = (u16*)alloc((size_t)Gc * Kc * Dc * 2);        // (512 x 2048)
    u16* woT  = (u16*)alloc((size_t)Dc * Hc * Kc * 2);        // (2048 x 2048)
    u16* qb   = (u16*)alloc((size_t)Bc * Tc * Hc * Kc * 2);
    u16* kb   = (u16*)alloc((size_t)Bc * Tc * Gc * Kc * 2);
    u16* vtb  = (u16*)alloc((size_t)Bc * Gc * Kc * Tc * 2);   // V^T [b][g][d][t]
    u16* attn = (u16*)alloc((size_t)Bc * Tc * Hc * Kc * 2);
    int* posb = (int*)alloc((size_t)Bc * Tc * 4);
    (void)ws_size; (void)in_sizes; (void)n_in; (void)out_size;

    const int M = Bc * Tc;   // 8192

    cvt_f2bf<<<(Bc * Tc * Dc) / 1024, 256, 0, stream>>>(hidden, hbf, Bc * Tc * Dc);
    transpose_f2bf<<<dim3(64, 64), 256, 0, stream>>>(wq, wqT, Dc, Hc * Kc);
    transpose_f2bf<<<dim3(16, 64), 256, 0, stream>>>(wk, wkT, Dc, Gc * Kc);
    transpose_f2bf<<<dim3(16, 64), 256, 0, stream>>>(wv, wvT, Dc, Gc * Kc);
    transpose_f2bf<<<dim3(64, 64), 256, 0, stream>>>(wo, woT, Hc * Kc, Dc);
    pos_kernel<<<(Bc * Tc) / 256, 256, 0, stream>>>(segids, posb);

    gemm_bt<<<dim3((Hc * Kc) / GBN, M / GBM), 256, 0, stream>>>(hbf, wqT, nullptr, qb, M, Hc * Kc, Dc);
    // fused K+V gemm: B^T = [wkT ; wvT] (adjacent allocations), N = 1024
    gemm_kv<<<dim3(1024 / GBN, M / GBM), 256, 0, stream>>>(hbf, wkT, kb, vtb, M, Dc);

    rms_rope<<<(M * Hc) / 4, 256, 0, stream>>>(qb, q_scale, posb, Hc);
    rms_rope<<<(M * Gc) / 4, 256, 0, stream>>>(kb, k_scale, posb, Gc);

    flash_attn<<<dim3(Tc / 64, Hc, Bc), 256, 0, stream>>>(qb, kb, vtb, segids, posb, attn);

    gemm_bt<<<dim3(Dc / GBN, M / GBM), 256, 0, stream>>>(attn, woT, out, nullptr, M, Dc, Hc * Kc);
}

// Round 5
// 627.308 us; speedup vs baseline: 1.0553x; 1.0318x over previous
//
#include <hip/hip_runtime.h>

typedef unsigned short u16;
typedef unsigned int u32;
using f32x4 = __attribute__((ext_vector_type(4))) float;
using bf16x8 = __attribute__((ext_vector_type(8))) __bf16;

constexpr int Bc = 4, Tc = 2048, Dc = 2048, Hc = 16, Gc = 4, Kc = 128;
constexpr float EPSc = 1e-6f;

__device__ __forceinline__ u16 f2bf(float f) {
    u32 u = __float_as_uint(f);
    u = (u + 0x7fffu + ((u >> 16) & 1u)) >> 16;
    return (u16)u;
}
__device__ __forceinline__ float bf2f(u16 h) {
    return __uint_as_float(((u32)h) << 16);
}

// async global->LDS, 16B per lane; LDS dest must be wave-uniform base + lane*16
__device__ __forceinline__ void async_ld16(void* lds, const void* g) {
    __builtin_amdgcn_global_load_lds(
        (const __attribute__((address_space(1))) unsigned int*)g,
        (__attribute__((address_space(3))) unsigned int*)lds, 16, 0, 0);
}

// ---------------- fp32 -> bf16 convert ----------------
__global__ __launch_bounds__(256) void cvt_f2bf(const float* __restrict__ in,
                                                u16* __restrict__ out, int n) {
    int i = (blockIdx.x * 256 + threadIdx.x) * 4;
    if (i >= n) return;
    float4 f = *(const float4*)(in + i);
    u16 r[4] = { f2bf(f.x), f2bf(f.y), f2bf(f.z), f2bf(f.w) };
    *(uint2*)(out + i) = *(uint2*)r;
}

// ------- transpose+convert: in (rows x cols) f32 -> out (cols x rows) bf16 -------
__global__ __launch_bounds__(256) void transpose_f2bf(const float* __restrict__ in,
                                                      u16* __restrict__ out,
                                                      int rows, int cols) {
    __shared__ float tile[32][33];
    int tx = threadIdx.x & 31, ty = threadIdx.x >> 5;
    int c0 = blockIdx.x * 32, r0 = blockIdx.y * 32;
#pragma unroll
    for (int j = 0; j < 4; j++)
        tile[ty + j * 8][tx] = in[(size_t)(r0 + ty + j * 8) * cols + c0 + tx];
    __syncthreads();
#pragma unroll
    for (int j = 0; j < 4; j++)
        out[(size_t)(c0 + ty + j * 8) * rows + r0 + tx] = f2bf(tile[tx][ty + j * 8]);
}

// ---------------- positions from (sorted) segment ids ----------------
__global__ void pos_kernel(const int* __restrict__ seg, int* __restrict__ pos) {
    int idx = blockIdx.x * 256 + threadIdx.x;
    if (idx >= Bc * Tc) return;
    int b = idx / Tc, t = idx - b * Tc;
    const int* s = seg + b * Tc;
    int v = s[t];
    int lo = 0, hi = t;
    while (lo < hi) { int mid = (lo + hi) >> 1; if (s[mid] < v) lo = mid + 1; else hi = mid; }
    pos[idx] = t - lo;   // t - seg_start
}

// ---------------- bf16 GEMM (m97 structure): C(MxN) = A(MxKd) * Bt(NxKd)^T ----------------
#define GBM 128
#define GBN 128
#define GBK 32

__global__ __launch_bounds__(256) void gemm_bt(const u16* __restrict__ A,
                                               const u16* __restrict__ Bt,
                                               float* __restrict__ Cf, u16* __restrict__ Cb,
                                               int M, int N, int Kd) {
    __shared__ __align__(16) u16 lA[GBM * GBK];   // unpadded: required by global_load_lds lane order
    __shared__ __align__(16) u16 lB[GBN * GBK];
    const int tid = threadIdx.x;
    const int m0 = blockIdx.y * GBM, n0 = blockIdx.x * GBN;
    const int wave = tid >> 6, lane = tid & 63;
    const int l16 = lane & 15, quad = lane >> 4;
    const int wm = (wave & 1) * 64, wn = (wave >> 1) * 64;

    const int c0 = tid, c1 = tid + 256;
    const u16* gA0 = A + (size_t)(m0 + (c0 >> 2)) * Kd + (c0 & 3) * 8;
    const u16* gA1 = A + (size_t)(m0 + (c1 >> 2)) * Kd + (c1 & 3) * 8;
    const u16* gB0 = Bt + (size_t)(n0 + (c0 >> 2)) * Kd + (c0 & 3) * 8;
    const u16* gB1 = Bt + (size_t)(n0 + (c1 >> 2)) * Kd + (c1 & 3) * 8;
    u16* sA0 = &lA[c0 * 8];
    u16* sA1 = &lA[c1 * 8];
    u16* sB0 = &lB[c0 * 8];
    u16* sB1 = &lB[c1 * 8];

    const f32x4 fz = {0.f, 0.f, 0.f, 0.f};
    f32x4 acc[4][4];
#pragma unroll
    for (int i = 0; i < 4; i++)
#pragma unroll
        for (int j = 0; j < 4; j++) acc[i][j] = fz;

    for (int k0 = 0; k0 < Kd; k0 += GBK) {
        __syncthreads();
        async_ld16(sA0, gA0 + k0);
        async_ld16(sA1, gA1 + k0);
        async_ld16(sB0, gB0 + k0);
        async_ld16(sB1, gB1 + k0);
        __syncthreads();
        bf16x8 af[4], bg[4];
#pragma unroll
        for (int i = 0; i < 4; i++) {
            af[i] = *(const bf16x8*)&lA[(wm + i * 16 + l16) * GBK + quad * 8];
            bg[i] = *(const bf16x8*)&lB[(wn + i * 16 + l16) * GBK + quad * 8];
        }
#pragma unroll
        for (int mi = 0; mi < 4; mi++)
#pragma unroll
            for (int ni = 0; ni < 4; ni++)
                acc[mi][ni] = __builtin_amdgcn_mfma_f32_16x16x32_bf16(af[mi], bg[ni], acc[mi][ni], 0, 0, 0);
    }

#pragma unroll
    for (int mi = 0; mi < 4; mi++)
#pragma unroll
        for (int ni = 0; ni < 4; ni++)
#pragma unroll
            for (int r = 0; r < 4; r++) {
                int row = m0 + wm + mi * 16 + quad * 4 + r;   // C/D: row=quad*4+reg
                int col = n0 + wn + ni * 16 + l16;            //      col=lane&15
                float v = acc[mi][ni][r];
                if (Cf) Cf[(size_t)row * N + col] = v;
                else    Cb[(size_t)row * N + col] = f2bf(v);
            }
}

// ------- merged QKV GEMM: N=3072 over [wqT;wkT;wvT]; Q->qb, K->kb, V->Vt[b][g][d][t] -------
__global__ __launch_bounds__(256) void gemm_qkv(const u16* __restrict__ A,
                                                const u16* __restrict__ Bt,
                                                u16* __restrict__ qb, u16* __restrict__ kb,
                                                u16* __restrict__ vtb, int M, int Kd) {
    __shared__ __align__(16) u16 lA[GBM * GBK];
    __shared__ __align__(16) u16 lB[GBN * GBK];
    const int tid = threadIdx.x;
    const int m0 = blockIdx.y * GBM, n0 = blockIdx.x * GBN;
    const int wave = tid >> 6, lane = tid & 63;
    const int l16 = lane & 15, quad = lane >> 4;
    const int wm = (wave & 1) * 64, wn = (wave >> 1) * 64;

    const int c0 = tid, c1 = tid + 256;
    const u16* gA0 = A + (size_t)(m0 + (c0 >> 2)) * Kd + (c0 & 3) * 8;
    const u16* gA1 = A + (size_t)(m0 + (c1 >> 2)) * Kd + (c1 & 3) * 8;
    const u16* gB0 = Bt + (size_t)(n0 + (c0 >> 2)) * Kd + (c0 & 3) * 8;
    const u16* gB1 = Bt + (size_t)(n0 + (c1 >> 2)) * Kd + (c1 & 3) * 8;
    u16* sA0 = &lA[c0 * 8];
    u16* sA1 = &lA[c1 * 8];
    u16* sB0 = &lB[c0 * 8];
    u16* sB1 = &lB[c1 * 8];

    const f32x4 fz = {0.f, 0.f, 0.f, 0.f};
    f32x4 acc[4][4];
#pragma unroll
    for (int i = 0; i < 4; i++)
#pragma unroll
        for (int j = 0; j < 4; j++) acc[i][j] = fz;

    for (int k0 = 0; k0 < Kd; k0 += GBK) {
        __syncthreads();
        async_ld16(sA0, gA0 + k0);
        async_ld16(sA1, gA1 + k0);
        async_ld16(sB0, gB0 + k0);
        async_ld16(sB1, gB1 + k0);
        __syncthreads();
        bf16x8 af[4], bg[4];
#pragma unroll
        for (int i = 0; i < 4; i++) {
            af[i] = *(const bf16x8*)&lA[(wm + i * 16 + l16) * GBK + quad * 8];
            bg[i] = *(const bf16x8*)&lB[(wn + i * 16 + l16) * GBK + quad * 8];
        }
#pragma unroll
        for (int mi = 0; mi < 4; mi++)
#pragma unroll
            for (int ni = 0; ni < 4; ni++)
                acc[mi][ni] = __builtin_amdgcn_mfma_f32_16x16x32_bf16(af[mi], bg[ni], acc[mi][ni], 0, 0, 0);
    }

    const int nbase = n0 + wn;   // 64-aligned; regions split at 2048 / 2560 (both 64-aligned)
    if (nbase < 2048) {
        // Q: qb[(b,t)][(h,d)] = [M][2048]
#pragma unroll
        for (int mi = 0; mi < 4; mi++)
#pragma unroll
            for (int ni = 0; ni < 4; ni++)
#pragma unroll
                for (int r = 0; r < 4; r++) {
                    int row = m0 + wm + mi * 16 + quad * 4 + r;
                    int col = nbase + ni * 16 + l16;
                    qb[(size_t)row * 2048 + col] = f2bf(acc[mi][ni][r]);
                }
    } else if (nbase < 2560) {
        // K: kb[(b,t)][(g,d)] = [M][512]
#pragma unroll
        for (int mi = 0; mi < 4; mi++)
#pragma unroll
            for (int ni = 0; ni < 4; ni++)
#pragma unroll
                for (int r = 0; r < 4; r++) {
                    int row = m0 + wm + mi * 16 + quad * 4 + r;
                    int col = nbase + ni * 16 + l16 - 2048;
                    kb[(size_t)row * 512 + col] = f2bf(acc[mi][ni][r]);
                }
    } else {
        // V: transposed Vt[b][g][d][t]; 4 consecutive t per lane -> 8B store
#pragma unroll
        for (int mi = 0; mi < 4; mi++)
#pragma unroll
            for (int ni = 0; ni < 4; ni++) {
                int nv = nbase + ni * 16 + l16 - 2560;
                int g = nv >> 7, d = nv & 127;
                int m = m0 + wm + mi * 16 + quad * 4;
                int b = m >> 11, t = m & 2047;
                u16 r4[4];
#pragma unroll
                for (int r = 0; r < 4; r++) r4[r] = f2bf(acc[mi][ni][r]);
                *(uint2*)&vtb[(((size_t)b * Gc + g) * Kc + d) * Tc + t] = *(uint2*)r4;
            }
    }
}

// ---------------- fused RMSNorm + RoPE (+ optional smul fold), in place ----------------
__global__ __launch_bounds__(256) void rms_rope(u16* __restrict__ X,
                                                const float* __restrict__ sc,
                                                const int* __restrict__ pos, int NH,
                                                float smul) {
    int row = blockIdx.x * 4 + (threadIdx.x >> 6);   // one wave per (b,t,head) row
    int lane = threadIdx.x & 63;
    int bt = row / NH;
    u16* xp = X + (size_t)row * Kc;
    float x1 = bf2f(xp[lane]), x2 = bf2f(xp[lane + 64]);   // rope pairs (j, j+64)
    float ss = x1 * x1 + x2 * x2;
#pragma unroll
    for (int m = 1; m < 64; m <<= 1) ss += __shfl_xor(ss, m, 64);
    float rn = rsqrtf(ss * (1.f / 128.f) + EPSc) * smul;   // fold attn scale into q
    float y1 = x1 * rn * sc[lane];
    float y2 = x2 * rn * sc[lane + 64];
    float inv_freq = expf(-logf(10000.f) * ((float)(2 * lane) * (1.f / 128.f)));
    float ang = (float)pos[bt] * inv_freq;
    float sv, cv;
    sincosf(ang, &sv, &cv);
    xp[lane]      = f2bf(y1 * cv - y2 * sv);
    xp[lane + 64] = f2bf(y2 * cv + y1 * sv);
}

// ---------------- flash attention: 64 q-rows per block, 64-wide s-tiles ----------------
#define KSTR 136   // 128+8: stride 68 dwords == 4 mod 32 -> 2-way on frag reads (free)
#define VSTR 72    // 64+8:  stride 36 dwords == 4 mod 32
#define PSTR 72

__global__ __launch_bounds__(256) void flash_attn(const u16* __restrict__ Qb,
                                                  const u16* __restrict__ Kb,
                                                  const u16* __restrict__ Vt,
                                                  const int* __restrict__ seg,
                                                  const int* __restrict__ pos,
                                                  u16* __restrict__ Ob) {
    __shared__ __align__(16) u16 lK[64 * KSTR];
    __shared__ __align__(16) u16 lVt[128 * VSTR];   // V transposed: [d][s]
    __shared__ __align__(16) u16 lP[64 * PSTR];     // [t][s]
    __shared__ float lAl[64];
    __shared__ float lLi[64];

    const int b = blockIdx.z, h = blockIdx.y, g = h >> 2;        // g = h / R, R=4
    const int q0 = ((int)gridDim.x - 1 - (int)blockIdx.x) * 64;  // heavy tiles first
    const int tid = threadIdx.x;
    const int wave = tid >> 6, lane = tid & 63;
    const int l16 = lane & 15, quad = lane >> 4;

    // Q A-fragments in registers (already scaled by K^-0.5 in rms_rope)
    bf16x8 qf[4];
#pragma unroll
    for (int kk = 0; kk < 4; kk++)
        qf[kk] = *(const bf16x8*)&Qb[((size_t)(b * Tc + q0 + wave * 16 + l16) * Hc + h) * Kc + kk * 32 + quad * 8];

    int tg[4], sgt[4];
#pragma unroll
    for (int r = 0; r < 4; r++) {
        tg[r] = q0 + wave * 16 + quad * 4 + r;
        sgt[r] = seg[b * Tc + tg[r]];
    }
    const bool segQuni = (seg[b * Tc + q0] == seg[b * Tc + q0 + 63]);

    float m_i[4], l_i[4];
#pragma unroll
    for (int r = 0; r < 4; r++) { m_i[r] = -1e30f; l_i[r] = 0.f; }
    const f32x4 fz = {0.f, 0.f, 0.f, 0.f};
    f32x4 oc[8];   // O^T C-tiles: row d = ni*16+quad*4+r, col t = wave*16+l16
#pragma unroll
    for (int i = 0; i < 8; i++) oc[i] = fz;

    const int seg_start_exact = q0 - pos[b * Tc + q0];   // first index of q0's segment
    const int s_begin = (seg_start_exact >> 6) << 6;     // tile-aligned (may include prev segment!)

    // prefetch first K/V tile into registers (overlaps with nothing yet, but primes the pipeline)
    uint4 kpre[4], vpre[4];
#pragma unroll
    for (int it = 0; it < 4; it++) {
        int c = tid + it * 256;
        kpre[it] = *(const uint4*)&Kb[((size_t)(b * Tc + s_begin + (c >> 4)) * Gc + g) * Kc + (c & 15) * 8];
        vpre[it] = *(const uint4*)&Vt[(((size_t)b * Gc + g) * Kc + (c >> 3)) * Tc + s_begin + (c & 7) * 8];
    }

    for (int s0 = s_begin; s0 <= q0; s0 += 64) {
        __syncthreads();   // prior iter's lK/lVt/lP reads complete
        // stage K tile (64 x 128) from prefetch regs, padded stride
#pragma unroll
        for (int it = 0; it < 4; it++) {
            int c = tid + it * 256;
            *(uint4*)&lK[(c >> 4) * KSTR + (c & 15) * 8] = kpre[it];
        }
        // stage Vt tile (128 x 64) from prefetch regs
#pragma unroll
        for (int it = 0; it < 4; it++) {
            int c = tid + it * 256;
            *(uint4*)&lVt[(c >> 3) * VSTR + (c & 7) * 8] = vpre[it];
        }
        // prefetch next tile: global loads in flight across this iter's compute
        if (s0 + 64 <= q0) {
#pragma unroll
            for (int it = 0; it < 4; it++) {
                int c = tid + it * 256;
                kpre[it] = *(const uint4*)&Kb[((size_t)(b * Tc + s0 + 64 + (c >> 4)) * Gc + g) * Kc + (c & 15) * 8];
                vpre[it] = *(const uint4*)&Vt[(((size_t)b * Gc + g) * Kc + (c >> 3)) * Tc + s0 + 64 + (c & 7) * 8];
            }
        }
        __syncthreads();   // staging visible

        // S = Q K^T
        f32x4 sacc[4];
#pragma unroll
        for (int nj = 0; nj < 4; nj++) sacc[nj] = fz;
#pragma unroll
        for (int kk = 0; kk < 4; kk++) {
#pragma unroll
            for (int nj = 0; nj < 4; nj++) {
                bf16x8 bk = *(const bf16x8*)&lK[(nj * 16 + l16) * KSTR + kk * 32 + quad * 8];
                sacc[nj] = __builtin_amdgcn_mfma_f32_16x16x32_bf16(qf[kk], bk, sacc[nj], 0, 0, 0);
            }
        }

        // Fast path only when whole s-tile provably passes both checks (note s_begin
        // is rounded DOWN: its tile can contain previous-segment tokens)
        const bool fast = segQuni && (s0 >= seg_start_exact) && (s0 + 64 <= q0);
        float rmax[4];
#pragma unroll
        for (int r = 0; r < 4; r++) rmax[r] = -1e30f;
        if (fast) {
#pragma unroll
            for (int nj = 0; nj < 4; nj++)
#pragma unroll
                for (int r = 0; r < 4; r++) rmax[r] = fmaxf(rmax[r], sacc[nj][r]);
        } else {
            int sgs[4];
#pragma unroll
            for (int nj = 0; nj < 4; nj++) sgs[nj] = seg[b * Tc + s0 + nj * 16 + l16];
#pragma unroll
            for (int nj = 0; nj < 4; nj++) {
                int sIdx = s0 + nj * 16 + l16;
#pragma unroll
                for (int r = 0; r < 4; r++) {
                    bool ok = (sIdx <= tg[r]) && (sgs[nj] == sgt[r]);
                    float x = ok ? sacc[nj][r] : -1e30f;
                    sacc[nj][r] = x;
                    rmax[r] = fmaxf(rmax[r], x);
                }
            }
        }
#pragma unroll
        for (int r = 0; r < 4; r++) {
            float v = rmax[r];
            v = fmaxf(v, __shfl_xor(v, 1, 64));
            v = fmaxf(v, __shfl_xor(v, 2, 64));
            v = fmaxf(v, __shfl_xor(v, 4, 64));
            v = fmaxf(v, __shfl_xor(v, 8, 64));
            rmax[r] = v;
        }
        float alpha[4];
#pragma unroll
        for (int r = 0; r < 4; r++) {
            float mnew = fmaxf(m_i[r], rmax[r]);
            alpha[r] = __expf(m_i[r] - mnew);
            m_i[r] = mnew;
        }
#pragma unroll
        for (int r = 0; r < 4; r++)
            if (l16 == r) lAl[wave * 16 + quad * 4 + r] = alpha[r];

        float psum[4] = {0.f, 0.f, 0.f, 0.f};
#pragma unroll
        for (int nj = 0; nj < 4; nj++) {
#pragma unroll
            for (int r = 0; r < 4; r++) {
                float x = sacc[nj][r];
                float p = (x > -1e29f) ? __expf(x - m_i[r]) : 0.f;
                psum[r] += p;
                lP[(wave * 16 + quad * 4 + r) * PSTR + nj * 16 + l16] = f2bf(p);
            }
        }
#pragma unroll
        for (int r = 0; r < 4; r++) {
            float v = psum[r];
            v += __shfl_xor(v, 1, 64);
            v += __shfl_xor(v, 2, 64);
            v += __shfl_xor(v, 4, 64);
            v += __shfl_xor(v, 8, 64);
            l_i[r] = l_i[r] * alpha[r] + v;
        }

        // O^T += V^T P^T (wave reads only its own lP rows / lAl entries: no barrier)
        float alphaL = lAl[wave * 16 + l16];
#pragma unroll
        for (int ni = 0; ni < 8; ni++)
#pragma unroll
            for (int r = 0; r < 4; r++) oc[ni][r] *= alphaL;
#pragma unroll
        for (int kk = 0; kk < 2; kk++) {
            bf16x8 bp = *(const bf16x8*)&lP[(wave * 16 + l16) * PSTR + kk * 32 + quad * 8];
#pragma unroll
            for (int ni = 0; ni < 8; ni++) {
                bf16x8 av = *(const bf16x8*)&lVt[(ni * 16 + l16) * VSTR + kk * 32 + quad * 8];
                oc[ni] = __builtin_amdgcn_mfma_f32_16x16x32_bf16(av, bp, oc[ni], 0, 0, 0);
            }
        }
    }

    // epilogue: O[t][d] = oc / l_i[t]
#pragma unroll
    for (int r = 0; r < 4; r++)
        if (l16 == r) lLi[wave * 16 + quad * 4 + r] = l_i[r];
    float invl = 1.f / lLi[wave * 16 + l16];
    size_t obase = ((size_t)(b * Tc + q0 + wave * 16 + l16) * Hc + h) * Kc;
#pragma unroll
    for (int ni = 0; ni < 8; ni++) {
        u16 r4[4];
#pragma unroll
        for (int r = 0; r < 4; r++) r4[r] = f2bf(oc[ni][r] * invl);
        *(uint2*)&Ob[obase + ni * 16 + quad * 4] = *(uint2*)r4;
    }
}

extern "C" void kernel_launch(void* const* d_in, const int* in_sizes, int n_in,
                              void* d_out, int out_size, void* d_ws, size_t ws_size,
                              hipStream_t stream) {
    const float* hidden  = (const float*)d_in[0];
    const float* wq      = (const float*)d_in[1];
    const float* wk      = (const float*)d_in[2];
    const float* wv      = (const float*)d_in[3];
    const float* wo      = (const float*)d_in[4];
    const float* q_scale = (const float*)d_in[5];
    const float* k_scale = (const float*)d_in[6];
    const int*   segids  = (const int*)d_in[7];
    float* out = (float*)d_out;

    char* ws = (char*)d_ws;
    size_t off = 0;
    auto alloc = [&](size_t bytes) -> void* {
        void* p = ws + off;
        off += (bytes + 255) & ~(size_t)255;
        return p;
    };
    u16* hbf  = (u16*)alloc((size_t)Bc * Tc * Dc * 2);        // hidden bf16
    u16* wqT  = (u16*)alloc((size_t)Hc * Kc * Dc * 2);        // (2048 x 2048) \  adjacent:
    u16* wkT  = (u16*)alloc((size_t)Gc * Kc * Dc * 2);        // (512 x 2048)   } one 3072-row B^T
    u16* wvT  = (u16*)alloc((size_t)Gc * Kc * Dc * 2);        // (512 x 2048)  /
    u16* woT  = (u16*)alloc((size_t)Dc * Hc * Kc * 2);        // (2048 x 2048)
    u16* qb   = (u16*)alloc((size_t)Bc * Tc * Hc * Kc * 2);
    u16* kb   = (u16*)alloc((size_t)Bc * Tc * Gc * Kc * 2);
    u16* vtb  = (u16*)alloc((size_t)Bc * Gc * Kc * Tc * 2);   // V^T [b][g][d][t]
    u16* attn = (u16*)alloc((size_t)Bc * Tc * Hc * Kc * 2);
    int* posb = (int*)alloc((size_t)Bc * Tc * 4);
    (void)ws_size; (void)in_sizes; (void)n_in; (void)out_size;

    const int M = Bc * Tc;   // 8192
    const float qsc = 0.08838834764831845f;   // K^-0.5 folded into q rms_rope

    cvt_f2bf<<<(Bc * Tc * Dc) / 1024, 256, 0, stream>>>(hidden, hbf, Bc * Tc * Dc);
    transpose_f2bf<<<dim3(64, 64), 256, 0, stream>>>(wq, wqT, Dc, Hc * Kc);
    transpose_f2bf<<<dim3(16, 64), 256, 0, stream>>>(wk, wkT, Dc, Gc * Kc);
    transpose_f2bf<<<dim3(16, 64), 256, 0, stream>>>(wv, wvT, Dc, Gc * Kc);
    transpose_f2bf<<<dim3(64, 64), 256, 0, stream>>>(wo, woT, Hc * Kc, Dc);
    pos_kernel<<<(Bc * Tc) / 256, 256, 0, stream>>>(segids, posb);

    // merged Q+K+V projection: N = 3072 over adjacent [wqT; wkT; wvT]
    gemm_qkv<<<dim3(3072 / GBN, M / GBM), 256, 0, stream>>>(hbf, wqT, qb, kb, vtb, M, Dc);

    rms_rope<<<(M * Hc) / 4, 256, 0, stream>>>(qb, q_scale, posb, Hc, qsc);
    rms_rope<<<(M * Gc) / 4, 256, 0, stream>>>(kb, k_scale, posb, Gc, 1.0f);

    flash_attn<<<dim3(Tc / 64, Hc, Bc), 256, 0, stream>>>(qb, kb, vtb, segids, posb, attn);

    gemm_bt<<<dim3(Dc / GBN, M / GBM), 256, 0, stream>>>(attn, woT, out, nullptr, M, Dc, Hc * Kc);
}